// Round 7
// baseline (388.751 us; speedup 1.0000x reference)
//
#include <hip/hip_runtime.h>
#include <stdint.h>

// Attention forward, B=4 S=2048 E=1024 H=16 D=64, causal. Outputs: o fp32 then
// attn.mean(heads) fp32.
//
// R12: kill the zero-overlap 2-barrier staging loops. k_proj/k_oproj: LDS
//      double-buffer + GLL prefetch of tile t+1 issued BEFORE compute of t,
//      ONE vmcnt-draining barrier per K-step (T3 minimum-2-phase recipe,
//      m230-V0). k_attnz: same idea reg-staged (k_mean's proven 1-barrier
//      pattern): barrier -> prefetch regs (t+1) -> compute buf[cur] ->
//      ds_write regs into buf[cur^1]. T2 swizzle deliberately NOT applied
//      (null at 2-phase per m252 regime gate).

#define BB 4
#define SS 2048
#define EE 1024
#define HH 16
#define DD 64
#define MTOT (BB*SS)          // 8192
#define HD (HH*DD)            // 1024
#define QKV_ELEMS ((size_t)MTOT*HD)

typedef float f32x4 __attribute__((ext_vector_type(4)));
typedef short bf16x8 __attribute__((ext_vector_type(8)));

#define GLL(g, l) __builtin_amdgcn_global_load_lds( \
    (const __attribute__((address_space(1))) void*)(g), \
    (__attribute__((address_space(3))) void*)(l), 16, 0, 0)

__device__ __forceinline__ short f2bf(float f) {
    unsigned u = __builtin_bit_cast(unsigned, f);
    u += 0x7FFFu + ((u >> 16) & 1u);   // RNE
    return (short)(u >> 16);
}

// ---------------- prep 1: x fp32 -> bf16 ----------------
__global__ __launch_bounds__(256) void k_xcast(const float* __restrict__ x,
                                               short* __restrict__ xbf) {
    int i = blockIdx.x*256 + threadIdx.x;
    float4 f = ((const float4*)x)[i];
    short4 s; s.x=f2bf(f.x); s.y=f2bf(f.y); s.z=f2bf(f.z); s.w=f2bf(f.w);
    ((short4*)xbf)[i] = s;
}

// ---------------- prep 2: W -> bf16, transposed to [n][k] ----------------
__global__ __launch_bounds__(256) void k_wprep(const float* __restrict__ wq,
        const float* __restrict__ wk, const float* __restrict__ wv,
        const float* __restrict__ wo, short* __restrict__ wtq,
        short* __restrict__ wto) {
    __shared__ short Tl[64][72];
    int t = threadIdx.x, x = blockIdx.x, y = blockIdx.y;
    int r4 = t >> 2, c4 = (t & 3) << 4;
    if (y < 48) {
        int which = y >> 4, h = y & 15, e0 = x*64;
        const float* src = (which==0?wq:which==1?wk:wv) + (size_t)h*EE*DD;
        const float* p = src + (size_t)(e0 + r4)*DD + c4;
        #pragma unroll
        for (int j = 0; j < 4; ++j) {
            float4 f = ((const float4*)p)[j];
            Tl[r4][c4+j*4+0]=f2bf(f.x); Tl[r4][c4+j*4+1]=f2bf(f.y);
            Tl[r4][c4+j*4+2]=f2bf(f.z); Tl[r4][c4+j*4+3]=f2bf(f.w);
        }
        __syncthreads();
        size_t nrow = ((size_t)(which*16 + h))*64 + r4;   // d = r4
        #pragma unroll
        for (int i = 0; i < 16; ++i)
            wtq[nrow*1024 + e0 + c4 + i] = Tl[c4+i][r4];
    } else {
        int h = y - 48, e0 = x*64;
        const float* src = wo + (size_t)h*DD*EE;          // [d][e]
        const float* p = src + (size_t)r4*EE + e0 + c4;   // d = r4
        #pragma unroll
        for (int j = 0; j < 4; ++j) {
            float4 f = ((const float4*)p)[j];
            Tl[r4][c4+j*4+0]=f2bf(f.x); Tl[r4][c4+j*4+1]=f2bf(f.y);
            Tl[r4][c4+j*4+2]=f2bf(f.z); Tl[r4][c4+j*4+3]=f2bf(f.w);
        }
        __syncthreads();
        #pragma unroll
        for (int i = 0; i < 16; ++i)
            wto[(size_t)(e0 + r4)*1024 + h*64 + c4 + i] = Tl[c4+i][r4];
    }
}

// ---------------- kernel 1: QKV projection ----------------
// grid (64, 24): 128x128 tile, BK=64. R12: LDS dbuf + prefetch-before-compute,
// 1 barrier per K-step. Q,K stored [b*S+pos][h*64+d]; V PRE-TRANSPOSED
// [b][h*64+d][pos].
__global__ __launch_bounds__(256) void k_proj(const short* __restrict__ xbf,
        const short* __restrict__ wtq, short* __restrict__ qkv) {
    __shared__ short As[2][128*64];
    __shared__ short Bs[2][128*64];
    int t = threadIdx.x;
    int m0 = blockIdx.x*128, n0 = blockIdx.y*128;
    int lane = t & 63, l15 = lane & 15, quad = lane >> 4;
    int wm = (t>>6) >> 1, wn = (t>>6) & 1;
    f32x4 acc[4][4];
    #pragma unroll
    for (int i=0;i<4;++i)
        #pragma unroll
        for (int c=0;c<4;++c) acc[i][c] = (f32x4){0,0,0,0};

    #pragma unroll
    for (int j = 0; j < 4; ++j) {                 // stage tile 0 -> buf 0
        int c = j*256 + t;
        int row = c >> 3, cg = c & 7;
        GLL(xbf + (size_t)(m0+row)*EE + cg*8, &As[0][(j*256 + (t & 192))*8]);
        GLL(wtq + (size_t)(n0+row)*EE + cg*8, &Bs[0][(j*256 + (t & 192))*8]);
    }
    for (int kt = 0; kt < 16; ++kt) {
        int cur = kt & 1;
        __syncthreads();                          // buf[cur] ready (vmcnt drained)
        if (kt < 15) {                            // issue next tile under compute
            int k0n = (kt+1)*64;
            #pragma unroll
            for (int j = 0; j < 4; ++j) {
                int c = j*256 + t;
                int row = c >> 3, cg = c & 7;
                GLL(xbf + (size_t)(m0+row)*EE + k0n + cg*8, &As[cur^1][(j*256 + (t & 192))*8]);
                GLL(wtq + (size_t)(n0+row)*EE + k0n + cg*8, &Bs[cur^1][(j*256 + (t & 192))*8]);
            }
        }
        #pragma unroll
        for (int kp = 0; kp < 64; kp += 32)
            #pragma unroll
            for (int i = 0; i < 4; ++i) {
                bf16x8 a = *(const bf16x8*)&As[cur][(wm*64 + i*16 + l15)*64 + kp + quad*8];
                #pragma unroll
                for (int c = 0; c < 4; ++c) {
                    bf16x8 b = *(const bf16x8*)&Bs[cur][(wn*64 + c*16 + l15)*64 + kp + quad*8];
                    acc[i][c] = __builtin_amdgcn_mfma_f32_16x16x32_bf16(a, b, acc[i][c], 0, 0, 0);
                }
            }
    }
    short* vt = qkv + 2*QKV_ELEMS;
    #pragma unroll
    for (int i = 0; i < 4; ++i)
        #pragma unroll
        for (int c = 0; c < 4; ++c) {
            int n = n0 + wn*64 + c*16 + l15;
            int row = m0 + wm*64 + i*16 + quad*4;
            if (n < 2048) {          // Q or K: [region][b*S+pos][h*64+d]
                #pragma unroll
                for (int r = 0; r < 4; ++r)
                    qkv[(size_t)(n>>10)*QKV_ELEMS + (size_t)(row+r)*HD + (n & 1023)] =
                        f2bf(acc[i][c][r]);
            } else {                 // V: [b][h*64+d][pos], pos contiguous in r
                short4 s4;
                s4.x = f2bf(acc[i][c][0]); s4.y = f2bf(acc[i][c][1]);
                s4.z = f2bf(acc[i][c][2]); s4.w = f2bf(acc[i][c][3]);
                int bb_ = row >> 11, pos = row & 2047;
                *(short4*)&vt[((size_t)bb_*HD + (n - 2048))*SS + pos] = s4;
            }
        }
}

// ---------- kernel 2: z = softmax(QK^T/8) V, no-max; exports c2=log2(l) ----------
// grid (8, 16, 4): q-tiles {qx, 15-qx} sequentially (uniform 34 tiles/block).
// R12: K/Vt double-buffered, ONE barrier per k-tile: barrier -> prefetch regs
// (t+1) -> compute buf[cur] -> ds_write regs -> buf[cur^1]. Swapped QK^T,
// packed b64 P-writes, natural Ps layout.
__global__ __launch_bounds__(256) void k_attnz(const short* __restrict__ qws,
        const short* __restrict__ kws, const short* __restrict__ vtg,
        short* __restrict__ zws, float* __restrict__ c2ws) {
    __shared__ short Ks[2][64][72];
    __shared__ short Vt[2][64][72];
    __shared__ short Ps[4][32][72];   // per-wave P tile (no barrier needed)
    int t = threadIdx.x;
    int h = blockIdx.y, b = blockIdx.z;
    int w = t>>6, lane = t&63, l15 = lane&15, quad = lane>>4;
    int sr = t>>2, sc = (t&3)<<4;

    const short* ksrc = kws + (size_t)(b*SS + sr)*HD + h*DD + sc;
    const short* vsrc = vtg + ((size_t)b*HD + h*DD + sr)*SS + sc;

    bf16x8 ones;
    #pragma unroll
    for (int i=0;i<8;++i) ones[i] = (short)0x3F80;   // bf16 1.0
    const float SC = 0.125f * 1.4426950408889634f;

    for (int half = 0; half < 2; ++half) {
        int qx = half ? (15 - (int)blockIdx.x) : (int)blockIdx.x;
        int q0 = qx*128;

        bf16x8 qr[2][2];                  // Q fragments, loop-invariant per half
        #pragma unroll
        for (int mf=0; mf<2; ++mf)
            #pragma unroll
            for (int kp=0; kp<2; ++kp)
                qr[mf][kp] = *(const bf16x8*)(qws +
                    (size_t)(b*SS + q0 + w*32 + mf*16 + l15)*HD + h*DD + kp*32 + quad*8);

        f32x4 accz[2][4];
        f32x4 accl[2];
        #pragma unroll
        for (int mf=0;mf<2;++mf) {
            accl[mf] = (f32x4){0,0,0,0};
            #pragma unroll
            for (int c=0;c<4;++c) accz[mf][c] = (f32x4){0,0,0,0};
        }
        int nk = q0/64 + 2;
        int qmax = q0 + w*32 + 31;

        // prologue: tile 0 -> buf 0 (half 1: protect prior half's last reads)
        uint4 pk0 = ((const uint4*)ksrc)[0], pk1 = ((const uint4*)ksrc)[1];
        uint4 pv0 = ((const uint4*)vsrc)[0], pv1 = ((const uint4*)vsrc)[1];
        if (half) __syncthreads();
        *(uint4*)&Ks[0][sr][sc] = pk0;  *(uint4*)&Ks[0][sr][sc+8] = pk1;
        *(uint4*)&Vt[0][sr][sc] = pv0;  *(uint4*)&Vt[0][sr][sc+8] = pv1;

        for (int kt = 0; kt < nk; ++kt) {
            int cur = kt & 1;
            int k0 = kt*64;
            __syncthreads();               // buf[cur] writes visible
            if (kt+1 < nk) {               // T14: issue next tile loads now
                const uint4* kn = (const uint4*)(ksrc + (size_t)(k0+64)*HD);
                const uint4* vn = (const uint4*)(vsrc + (k0+64));
                pk0=kn[0]; pk1=kn[1]; pv0=vn[0]; pv1=vn[1];
            }
            if (k0 <= qmax) {
                // QK^T swapped: s[mf][c] -> col(l15)=q-row(mf*16+l15),
                // row(quad*4+r)=k-pos(c*16+quad*4+r)
                f32x4 s[2][4];
                #pragma unroll
                for (int mf=0;mf<2;++mf)
                    #pragma unroll
                    for (int c=0;c<4;++c) s[mf][c] = (f32x4){0,0,0,0};
                __builtin_amdgcn_s_setprio(1);
                #pragma unroll
                for (int c=0;c<4;++c)
                    #pragma unroll
                    for (int kp=0;kp<2;++kp) {
                        bf16x8 aK = *(const bf16x8*)&Ks[cur][c*16+l15][kp*32+quad*8];
                        s[0][c] = __builtin_amdgcn_mfma_f32_16x16x32_bf16(aK, qr[0][kp], s[0][c], 0, 0, 0);
                        s[1][c] = __builtin_amdgcn_mfma_f32_16x16x32_bf16(aK, qr[1][kp], s[1][c], 0, 0, 0);
                    }
                __builtin_amdgcn_s_setprio(0);
                // P epilogue: 4 consecutive k per lane -> packed b64, natural layout.
                #pragma unroll
                for (int mf=0;mf<2;++mf) {
                    int qg = q0 + w*32 + mf*16 + l15;
                    #pragma unroll
                    for (int c=0;c<4;++c) {
                        int kb = k0 + c*16 + quad*4;
                        short4 s4;
                        #pragma unroll
                        for (int r=0;r<4;++r) {
                            float p_ = (kb + r <= qg) ? __builtin_amdgcn_exp2f(s[mf][c][r]*SC) : 0.0f;
                            ((short*)&s4)[r] = f2bf(p_);
                        }
                        *(short4*)&Ps[w][mf*16 + l15][c*16 + quad*4] = s4;
                    }
                }
                // Ps is wave-private: HW lgkmcnt ordering suffices, no barrier.
                __builtin_amdgcn_s_setprio(1);
                #pragma unroll
                for (int kp=0;kp<2;++kp) {
                    bf16x8 pa0 = *(const bf16x8*)&Ps[w][l15][kp*32+quad*8];
                    bf16x8 pa1 = *(const bf16x8*)&Ps[w][16+l15][kp*32+quad*8];
                    #pragma unroll
                    for (int cc=0;cc<4;++cc) {
                        bf16x8 vb = *(const bf16x8*)&Vt[cur][cc*16+l15][kp*32+quad*8];
                        accz[0][cc] = __builtin_amdgcn_mfma_f32_16x16x32_bf16(pa0, vb, accz[0][cc], 0, 0, 0);
                        accz[1][cc] = __builtin_amdgcn_mfma_f32_16x16x32_bf16(pa1, vb, accz[1][cc], 0, 0, 0);
                    }
                    accl[0] = __builtin_amdgcn_mfma_f32_16x16x32_bf16(pa0, ones, accl[0], 0, 0, 0);
                    accl[1] = __builtin_amdgcn_mfma_f32_16x16x32_bf16(pa1, ones, accl[1], 0, 0, 0);
                }
                __builtin_amdgcn_s_setprio(0);
            }
            if (kt+1 < nk) {               // write next tile under/after compute
                *(uint4*)&Ks[cur^1][sr][sc] = pk0;  *(uint4*)&Ks[cur^1][sr][sc+8] = pk1;
                *(uint4*)&Vt[cur^1][sr][sc] = pv0;  *(uint4*)&Vt[cur^1][sr][sc+8] = pv1;
            }
        }
        #pragma unroll
        for (int mf=0;mf<2;++mf) {
            float il[4];
            #pragma unroll
            for (int r=0;r<4;++r) il[r] = 1.0f / accl[mf][r];
            #pragma unroll
            for (int cc=0;cc<4;++cc)
                #pragma unroll
                for (int r=0;r<4;++r) {
                    int row = q0 + w*32 + mf*16 + quad*4 + r;
                    zws[(size_t)(b*SS+row)*HD + h*DD + cc*16 + l15] = f2bf(accz[mf][cc][r]*il[r]);
                }
            if (l15 == 0) {
                size_t base = ((size_t)(b*HH+h))*SS + q0 + w*32 + mf*16 + quad*4;
                #pragma unroll
                for (int r=0;r<4;++r)
                    c2ws[base+r] = __log2f(accl[mf][r]);
            }
        }
    }
}

// ---------------- kernel 3: attn mean over heads ----------------
// grid (32, 32, 4). Upper-triangle blocks write zeros. Only K staged in LDS
// (each wave reads just its own 16 Q rows -> Q frags prefetched to regs).
__global__ __launch_bounds__(256) void k_mean(const short* __restrict__ qws,
        const short* __restrict__ kws, const float* __restrict__ c2ws,
        float* __restrict__ attn_out) {
    int b = blockIdx.z;
    int qx = (b & 1) ? (31 - (int)blockIdx.x) : (int)blockIdx.x;
    int q0 = qx*64, k0 = blockIdx.y*64;
    int t = threadIdx.x;
    if (k0 > q0) {
        int r = t >> 2, cq = (t & 3) << 4;
        float4 z4 = {0.f,0.f,0.f,0.f};
        float* dst = attn_out + ((size_t)(b*SS + q0 + r))*SS + k0 + cq;
        #pragma unroll
        for (int j = 0; j < 4; ++j) ((float4*)dst)[j] = z4;
        return;
    }
    __shared__ short Ksm[2][64][72];
    __shared__ float c2s[16][64];
    int w = t>>6, lane = t&63, l15 = lane&15, quad = lane>>4;
    int sr = t>>2, sc = (t&3)<<4;
    #pragma unroll
    for (int i = 0; i < 4; ++i) {
        int idx = t + i*256;
        int hh = idx >> 6, r = idx & 63;
        c2s[hh][r] = c2ws[((size_t)(b*HH+hh))*SS + q0 + r];
    }
    const short* ksrc = kws + (size_t)(b*SS + k0 + sr)*HD + sc;          // + h*64
    const short* qsrc = qws + (size_t)(b*SS + q0 + w*16 + l15)*HD + quad*8;  // + h*64

    // prologue: stage head 0 K, load head 0 Q frags
    {
        const uint4* kp = (const uint4*)ksrc;
        uint4 c = kp[0], d = kp[1];
        *(uint4*)&Ksm[0][sr][sc] = c;  *(uint4*)&Ksm[0][sr][sc+8] = d;
    }
    bf16x8 qc0 = *(const bf16x8*)(qsrc);
    bf16x8 qc1 = *(const bf16x8*)(qsrc + 32);

    const float SC = 0.125f * 1.4426950408889634f;
    int rowg0 = q0 + w*16 + quad*4;
    f32x4 acc[4] = { {0,0,0,0},{0,0,0,0},{0,0,0,0},{0,0,0,0} };

    for (int h = 0; h < HH; ++h) {
        int cur = h & 1;
        __syncthreads();               // Ksm[cur] (and c2s on h=0) ready
        uint4 nka, nkb; bf16x8 nq0, nq1;
        if (h < HH-1) {
            const uint4* kn = (const uint4*)(ksrc + (h+1)*64);
            nka = kn[0]; nkb = kn[1];
            nq0 = *(const bf16x8*)(qsrc + (h+1)*64);
            nq1 = *(const bf16x8*)(qsrc + (h+1)*64 + 32);
        }

        f32x4 c2 = *(const f32x4*)&c2s[h][w*16 + quad*4];
        #pragma unroll
        for (int ns = 0; ns < 4; ++ns) {
            bf16x8 b0 = *(const bf16x8*)&Ksm[cur][ns*16+l15][quad*8];
            bf16x8 b1 = *(const bf16x8*)&Ksm[cur][ns*16+l15][quad*8+32];
            f32x4 s = {0,0,0,0};
            s = __builtin_amdgcn_mfma_f32_16x16x32_bf16(qc0, b0, s, 0, 0, 0);
            s = __builtin_amdgcn_mfma_f32_16x16x32_bf16(qc1, b1, s, 0, 0, 0);
            int col = k0 + ns*16 + l15;
            #pragma unroll
            for (int r = 0; r < 4; ++r) {
                float ex = __builtin_amdgcn_exp2f(s[r]*SC - c2[r]);
                acc[ns][r] += (col <= rowg0 + r) ? ex : 0.0f;
            }
        }

        if (h < HH-1) {
            int nxt = cur ^ 1;
            *(uint4*)&Ksm[nxt][sr][sc]   = nka;  *(uint4*)&Ksm[nxt][sr][sc+8] = nkb;
            qc0 = nq0; qc1 = nq1;
        }
    }
    #pragma unroll
    for (int ns = 0; ns < 4; ++ns)
        #pragma unroll
        for (int r = 0; r < 4; ++r)
            attn_out[((size_t)(b*SS + rowg0 + r))*SS + k0 + ns*16 + l15] =
                acc[ns][r] * 0.0625f;
}

// ---------------- kernel 4: output projection ----------------
// grid (64, 8): 128x128 tile, BK=64. R12: LDS dbuf + prefetch, 1 barrier/step.
__global__ __launch_bounds__(256) void k_oproj(const short* __restrict__ zws,
        const short* __restrict__ wto, float* __restrict__ outp) {
    __shared__ short As[2][128*64];
    __shared__ short Bs[2][128*64];
    int t = threadIdx.x;
    int m0 = blockIdx.x*128, n0 = blockIdx.y*128;
    int lane = t & 63, l15 = lane & 15, quad = lane >> 4;
    int wm = (t>>6) >> 1, wn = (t>>6) & 1;
    f32x4 acc[4][4];
    #pragma unroll
    for (int i=0;i<4;++i)
        #pragma unroll
        for (int c=0;c<4;++c) acc[i][c] = (f32x4){0,0,0,0};

    #pragma unroll
    for (int j = 0; j < 4; ++j) {                 // stage tile 0 -> buf 0
        int c = j*256 + t;
        int row = c >> 3, cg = c & 7;
        GLL(zws + (size_t)(m0+row)*HD + cg*8, &As[0][(j*256 + (t & 192))*8]);
        GLL(wto + (size_t)(n0+row)*HD + cg*8, &Bs[0][(j*256 + (t & 192))*8]);
    }
    for (int kt = 0; kt < 16; ++kt) {
        int cur = kt & 1;
        __syncthreads();                          // buf[cur] ready
        if (kt < 15) {
            int k0n = (kt+1)*64;
            #pragma unroll
            for (int j = 0; j < 4; ++j) {
                int c = j*256 + t;
                int row = c >> 3, cg = c & 7;
                GLL(zws + (size_t)(m0+row)*HD + k0n + cg*8, &As[cur^1][(j*256 + (t & 192))*8]);
                GLL(wto + (size_t)(n0+row)*HD + k0n + cg*8, &Bs[cur^1][(j*256 + (t & 192))*8]);
            }
        }
        #pragma unroll
        for (int kp = 0; kp < 64; kp += 32)
            #pragma unroll
            for (int i = 0; i < 4; ++i) {
                bf16x8 a = *(const bf16x8*)&As[cur][(wm*64 + i*16 + l15)*64 + kp + quad*8];
                #pragma unroll
                for (int c = 0; c < 4; ++c) {
                    bf16x8 b = *(const bf16x8*)&Bs[cur][(wn*64 + c*16 + l15)*64 + kp + quad*8];
                    acc[i][c] = __builtin_amdgcn_mfma_f32_16x16x32_bf16(a, b, acc[i][c], 0, 0, 0);
                }
            }
    }
    #pragma unroll
    for (int i = 0; i < 4; ++i)
        #pragma unroll
        for (int c = 0; c < 4; ++c)
            #pragma unroll
            for (int r = 0; r < 4; ++r) {
                int row = m0 + wm*64 + i*16 + quad*4 + r;
                int n = n0 + wn*64 + c*16 + l15;
                outp[(size_t)row*EE + n] = acc[i][c][r];
            }
}

extern "C" void kernel_launch(void* const* d_in, const int* in_sizes, int n_in,
                              void* d_out, int out_size, void* d_ws, size_t ws_size,
                              hipStream_t stream) {
    const float* x  = (const float*)d_in[0];
    const float* wq = (const float*)d_in[1];
    const float* wk = (const float*)d_in[2];
    const float* wv = (const float*)d_in[3];
    const float* wo = (const float*)d_in[4];

    short* xbf = (short*)d_ws;                 // 16 MB; reused as z after k_proj
    short* qb  = xbf + QKV_ELEMS;
    short* kb  = qb + QKV_ELEMS;
    short* vtb = kb + QKV_ELEMS;               // V^T [b][h*64+d][pos]
    short* wtq = vtb + QKV_ELEMS;              // 3072x1024 bf16 (n-major)
    short* wto = wtq + (size_t)3*1024*1024;    // 1024x1024 bf16 (n-major)
    float* c2w = (float*)(wto + (size_t)1024*1024);
    short* zb  = xbf;                          // alias: x consumed by k_proj

    float* o = (float*)d_out;
    float* attn_out = o + (size_t)MTOT*EE;

    k_xcast<<<dim3(8192),     256, 0, stream>>>(x, xbf);
    k_wprep<<<dim3(16,64),    256, 0, stream>>>(wq, wk, wv, wo, wtq, wto);
    k_proj <<<dim3(64,24),    256, 0, stream>>>(xbf, wtq, qb);
    k_attnz<<<dim3(8,16,4),   256, 0, stream>>>(qb, kb, vtb, zb, c2w);
    k_mean <<<dim3(32,32,4),  256, 0, stream>>>(qb, kb, c2w, attn_out);
    k_oproj<<<dim3(64,8),     256, 0, stream>>>(zb, wto, o);
}

// Round 8
// 349.369 us; speedup vs baseline: 1.1127x; 1.1127x over previous
//
#include <hip/hip_runtime.h>
#include <stdint.h>

// Attention forward, B=4 S=2048 E=1024 H=16 D=64, causal. Outputs: o fp32 then
// attn.mean(heads) fp32.
//
// R13: revert R12's dbuf (m99/m132 reproduced: no overlap gain, LDS 2x cost).
//      k_proj/k_oproj row-major [128][64] tile has row stride 128B = full bank
//      wrap -> 16-way conflict on every ds_read_b128 (the 1.89e7 counter).
//      T2 fix rule-21 style: LDS stays linear, global SOURCE col-group
//      pre-swizzled cg^(row&7) at GLL time, read applies same XOR -> 2-way
//      (free). k_attnz/k_mean keep [72]-padded layouts (already spread).

#define BB 4
#define SS 2048
#define EE 1024
#define HH 16
#define DD 64
#define MTOT (BB*SS)          // 8192
#define HD (HH*DD)            // 1024
#define QKV_ELEMS ((size_t)MTOT*HD)

typedef float f32x4 __attribute__((ext_vector_type(4)));
typedef short bf16x8 __attribute__((ext_vector_type(8)));

#define GLL(g, l) __builtin_amdgcn_global_load_lds( \
    (const __attribute__((address_space(1))) void*)(g), \
    (__attribute__((address_space(3))) void*)(l), 16, 0, 0)

__device__ __forceinline__ short f2bf(float f) {
    unsigned u = __builtin_bit_cast(unsigned, f);
    u += 0x7FFFu + ((u >> 16) & 1u);   // RNE
    return (short)(u >> 16);
}

// ---------------- prep 1: x fp32 -> bf16 ----------------
__global__ __launch_bounds__(256) void k_xcast(const float* __restrict__ x,
                                               short* __restrict__ xbf) {
    int i = blockIdx.x*256 + threadIdx.x;
    float4 f = ((const float4*)x)[i];
    short4 s; s.x=f2bf(f.x); s.y=f2bf(f.y); s.z=f2bf(f.z); s.w=f2bf(f.w);
    ((short4*)xbf)[i] = s;
}

// ---------------- prep 2: W -> bf16, transposed to [n][k] ----------------
__global__ __launch_bounds__(256) void k_wprep(const float* __restrict__ wq,
        const float* __restrict__ wk, const float* __restrict__ wv,
        const float* __restrict__ wo, short* __restrict__ wtq,
        short* __restrict__ wto) {
    __shared__ short Tl[64][72];
    int t = threadIdx.x, x = blockIdx.x, y = blockIdx.y;
    int r4 = t >> 2, c4 = (t & 3) << 4;
    if (y < 48) {
        int which = y >> 4, h = y & 15, e0 = x*64;
        const float* src = (which==0?wq:which==1?wk:wv) + (size_t)h*EE*DD;
        const float* p = src + (size_t)(e0 + r4)*DD + c4;
        #pragma unroll
        for (int j = 0; j < 4; ++j) {
            float4 f = ((const float4*)p)[j];
            Tl[r4][c4+j*4+0]=f2bf(f.x); Tl[r4][c4+j*4+1]=f2bf(f.y);
            Tl[r4][c4+j*4+2]=f2bf(f.z); Tl[r4][c4+j*4+3]=f2bf(f.w);
        }
        __syncthreads();
        size_t nrow = ((size_t)(which*16 + h))*64 + r4;   // d = r4
        #pragma unroll
        for (int i = 0; i < 16; ++i)
            wtq[nrow*1024 + e0 + c4 + i] = Tl[c4+i][r4];
    } else {
        int h = y - 48, e0 = x*64;
        const float* src = wo + (size_t)h*DD*EE;          // [d][e]
        const float* p = src + (size_t)r4*EE + e0 + c4;   // d = r4
        #pragma unroll
        for (int j = 0; j < 4; ++j) {
            float4 f = ((const float4*)p)[j];
            Tl[r4][c4+j*4+0]=f2bf(f.x); Tl[r4][c4+j*4+1]=f2bf(f.y);
            Tl[r4][c4+j*4+2]=f2bf(f.z); Tl[r4][c4+j*4+3]=f2bf(f.w);
        }
        __syncthreads();
        #pragma unroll
        for (int i = 0; i < 16; ++i)
            wto[(size_t)(e0 + r4)*1024 + h*64 + c4 + i] = Tl[c4+i][r4];
    }
}

// ---------------- kernel 1: QKV projection ----------------
// grid (64, 24): 128x128 tile, BK=64, single-buffer (R11 structure).
// T2 fix: source col-group XOR-swizzled at GLL, same XOR on read.
// Q,K stored [b*S+pos][h*64+d]; V PRE-TRANSPOSED [b][h*64+d][pos].
__global__ __launch_bounds__(256) void k_proj(const short* __restrict__ xbf,
        const short* __restrict__ wtq, short* __restrict__ qkv) {
    __shared__ short As[128*64];
    __shared__ short Bs[128*64];
    int t = threadIdx.x;
    int m0 = blockIdx.x*128, n0 = blockIdx.y*128;
    int lane = t & 63, l15 = lane & 15, quad = lane >> 4;
    int wm = (t>>6) >> 1, wn = (t>>6) & 1;
    f32x4 acc[4][4];
    #pragma unroll
    for (int i=0;i<4;++i)
        #pragma unroll
        for (int c=0;c<4;++c) acc[i][c] = (f32x4){0,0,0,0};

    for (int k0 = 0; k0 < EE; k0 += 64) {
        __syncthreads();
        #pragma unroll
        for (int j = 0; j < 4; ++j) {
            int c = j*256 + t;
            int row = c >> 3, cg = c & 7;
            int cgs = cg ^ (row & 7);            // pre-swizzled source group
            GLL(xbf + (size_t)(m0+row)*EE + k0 + cgs*8, &As[(j*256 + (t & 192))*8]);
            GLL(wtq + (size_t)(n0+row)*EE + k0 + cgs*8, &Bs[(j*256 + (t & 192))*8]);
        }
        __syncthreads();
        #pragma unroll
        for (int kp = 0; kp < 64; kp += 32) {
            int pg = ((((kp>>3) + quad) ^ (l15 & 7)) << 3);   // swizzled read grp
            #pragma unroll
            for (int i = 0; i < 4; ++i) {
                bf16x8 a = *(const bf16x8*)&As[(wm*64 + i*16 + l15)*64 + pg];
                #pragma unroll
                for (int c = 0; c < 4; ++c) {
                    bf16x8 b = *(const bf16x8*)&Bs[(wn*64 + c*16 + l15)*64 + pg];
                    acc[i][c] = __builtin_amdgcn_mfma_f32_16x16x32_bf16(a, b, acc[i][c], 0, 0, 0);
                }
            }
        }
    }
    short* vt = qkv + 2*QKV_ELEMS;
    #pragma unroll
    for (int i = 0; i < 4; ++i)
        #pragma unroll
        for (int c = 0; c < 4; ++c) {
            int n = n0 + wn*64 + c*16 + l15;
            int row = m0 + wm*64 + i*16 + quad*4;
            if (n < 2048) {          // Q or K: [region][b*S+pos][h*64+d]
                #pragma unroll
                for (int r = 0; r < 4; ++r)
                    qkv[(size_t)(n>>10)*QKV_ELEMS + (size_t)(row+r)*HD + (n & 1023)] =
                        f2bf(acc[i][c][r]);
            } else {                 // V: [b][h*64+d][pos], pos contiguous in r
                short4 s4;
                s4.x = f2bf(acc[i][c][0]); s4.y = f2bf(acc[i][c][1]);
                s4.z = f2bf(acc[i][c][2]); s4.w = f2bf(acc[i][c][3]);
                int bb_ = row >> 11, pos = row & 2047;
                *(short4*)&vt[((size_t)bb_*HD + (n - 2048))*SS + pos] = s4;
            }
        }
}

// ---------- kernel 2: z = softmax(QK^T/8) V, no-max; exports c2=log2(l) ----------
// grid (8, 16, 4): q-tiles {qx, 15-qx} sequentially (uniform 34 tiles/block,
// R11 structure). Swapped QK^T (mfma(K,Q)) -> packed b64 P-writes, natural Ps
// layout ([72] pad = conflict floor). T14 prefetch, setprio.
__global__ __launch_bounds__(256) void k_attnz(const short* __restrict__ qws,
        const short* __restrict__ kws, const short* __restrict__ vtg,
        short* __restrict__ zws, float* __restrict__ c2ws) {
    __shared__ short Ks[64][72];
    __shared__ short Vt[64][72];
    __shared__ short Ps[4][32][72];   // per-wave P tile (no barrier needed)
    int t = threadIdx.x;
    int h = blockIdx.y, b = blockIdx.z;
    int w = t>>6, lane = t&63, l15 = lane&15, quad = lane>>4;
    int sr = t>>2, sc = (t&3)<<4;

    const short* ksrc = kws + (size_t)(b*SS + sr)*HD + h*DD + sc;
    const short* vsrc = vtg + ((size_t)b*HD + h*DD + sr)*SS + sc;

    bf16x8 ones;
    #pragma unroll
    for (int i=0;i<8;++i) ones[i] = (short)0x3F80;   // bf16 1.0
    const float SC = 0.125f * 1.4426950408889634f;

    for (int half = 0; half < 2; ++half) {
        int qx = half ? (15 - (int)blockIdx.x) : (int)blockIdx.x;
        int q0 = qx*128;

        bf16x8 qr[2][2];                  // Q fragments, loop-invariant per half
        #pragma unroll
        for (int mf=0; mf<2; ++mf)
            #pragma unroll
            for (int kp=0; kp<2; ++kp)
                qr[mf][kp] = *(const bf16x8*)(qws +
                    (size_t)(b*SS + q0 + w*32 + mf*16 + l15)*HD + h*DD + kp*32 + quad*8);

        f32x4 accz[2][4];
        f32x4 accl[2];
        #pragma unroll
        for (int mf=0;mf<2;++mf) {
            accl[mf] = (f32x4){0,0,0,0};
            #pragma unroll
            for (int c=0;c<4;++c) accz[mf][c] = (f32x4){0,0,0,0};
        }
        int nk = q0/64 + 2;
        int qmax = q0 + w*32 + 31;

        uint4 pk0 = ((const uint4*)ksrc)[0], pk1 = ((const uint4*)ksrc)[1];
        uint4 pv0 = ((const uint4*)vsrc)[0], pv1 = ((const uint4*)vsrc)[1];

        for (int kt = 0; kt < nk; ++kt) {
            int k0 = kt*64;
            __syncthreads();               // prior compute done reading LDS
            *(uint4*)&Ks[sr][sc]   = pk0;  *(uint4*)&Ks[sr][sc+8] = pk1;
            *(uint4*)&Vt[sr][sc]   = pv0;  *(uint4*)&Vt[sr][sc+8] = pv1;
            __syncthreads();               // tile ready
            if (kt+1 < nk) {               // T14: issue next tile under compute
                const uint4* kn = (const uint4*)(ksrc + (size_t)(k0+64)*HD);
                const uint4* vn = (const uint4*)(vsrc + (k0+64));
                pk0=kn[0]; pk1=kn[1]; pv0=vn[0]; pv1=vn[1];
            }
            if (k0 > qmax) continue;       // fully masked for this wave

            // QK^T swapped: s[mf][c] -> col(l15)=q-row(mf*16+l15),
            // row(quad*4+r)=k-pos(c*16+quad*4+r)
            f32x4 s[2][4];
            #pragma unroll
            for (int mf=0;mf<2;++mf)
                #pragma unroll
                for (int c=0;c<4;++c) s[mf][c] = (f32x4){0,0,0,0};
            __builtin_amdgcn_s_setprio(1);
            #pragma unroll
            for (int c=0;c<4;++c)
                #pragma unroll
                for (int kp=0;kp<2;++kp) {
                    bf16x8 aK = *(const bf16x8*)&Ks[c*16+l15][kp*32+quad*8];
                    s[0][c] = __builtin_amdgcn_mfma_f32_16x16x32_bf16(aK, qr[0][kp], s[0][c], 0, 0, 0);
                    s[1][c] = __builtin_amdgcn_mfma_f32_16x16x32_bf16(aK, qr[1][kp], s[1][c], 0, 0, 0);
                }
            __builtin_amdgcn_s_setprio(0);
            // P epilogue: 4 consecutive k per lane -> packed b64 write, natural layout.
            #pragma unroll
            for (int mf=0;mf<2;++mf) {
                int qg = q0 + w*32 + mf*16 + l15;
                #pragma unroll
                for (int c=0;c<4;++c) {
                    int kb = k0 + c*16 + quad*4;
                    short4 s4;
                    #pragma unroll
                    for (int r=0;r<4;++r) {
                        float p_ = (kb + r <= qg) ? __builtin_amdgcn_exp2f(s[mf][c][r]*SC) : 0.0f;
                        ((short*)&s4)[r] = f2bf(p_);
                    }
                    *(short4*)&Ps[w][mf*16 + l15][c*16 + quad*4] = s4;
                }
            }
            // Ps is wave-private: HW lgkmcnt ordering suffices, no barrier.
            __builtin_amdgcn_s_setprio(1);
            #pragma unroll
            for (int kp=0;kp<2;++kp) {
                bf16x8 pa0 = *(const bf16x8*)&Ps[w][l15][kp*32+quad*8];
                bf16x8 pa1 = *(const bf16x8*)&Ps[w][16+l15][kp*32+quad*8];
                #pragma unroll
                for (int cc=0;cc<4;++cc) {
                    bf16x8 vb = *(const bf16x8*)&Vt[cc*16+l15][kp*32+quad*8];
                    accz[0][cc] = __builtin_amdgcn_mfma_f32_16x16x32_bf16(pa0, vb, accz[0][cc], 0, 0, 0);
                    accz[1][cc] = __builtin_amdgcn_mfma_f32_16x16x32_bf16(pa1, vb, accz[1][cc], 0, 0, 0);
                }
                accl[0] = __builtin_amdgcn_mfma_f32_16x16x32_bf16(pa0, ones, accl[0], 0, 0, 0);
                accl[1] = __builtin_amdgcn_mfma_f32_16x16x32_bf16(pa1, ones, accl[1], 0, 0, 0);
            }
            __builtin_amdgcn_s_setprio(0);
        }
        #pragma unroll
        for (int mf=0;mf<2;++mf) {
            float il[4];
            #pragma unroll
            for (int r=0;r<4;++r) il[r] = 1.0f / accl[mf][r];
            #pragma unroll
            for (int cc=0;cc<4;++cc)
                #pragma unroll
                for (int r=0;r<4;++r) {
                    int row = q0 + w*32 + mf*16 + quad*4 + r;
                    zws[(size_t)(b*SS+row)*HD + h*DD + cc*16 + l15] = f2bf(accz[mf][cc][r]*il[r]);
                }
            if (l15 == 0) {
                size_t base = ((size_t)(b*HH+h))*SS + q0 + w*32 + mf*16 + quad*4;
                #pragma unroll
                for (int r=0;r<4;++r)
                    c2ws[base+r] = __log2f(accl[mf][r]);
            }
        }
    }
}

// ---------------- kernel 3: attn mean over heads ----------------
// grid (32, 32, 4). Upper-triangle blocks write zeros. Only K staged in LDS
// (each wave reads just its own 16 Q rows -> Q frags prefetched to regs).
__global__ __launch_bounds__(256) void k_mean(const short* __restrict__ qws,
        const short* __restrict__ kws, const float* __restrict__ c2ws,
        float* __restrict__ attn_out) {
    int b = blockIdx.z;
    int qx = (b & 1) ? (31 - (int)blockIdx.x) : (int)blockIdx.x;
    int q0 = qx*64, k0 = blockIdx.y*64;
    int t = threadIdx.x;
    if (k0 > q0) {
        int r = t >> 2, cq = (t & 3) << 4;
        float4 z4 = {0.f,0.f,0.f,0.f};
        float* dst = attn_out + ((size_t)(b*SS + q0 + r))*SS + k0 + cq;
        #pragma unroll
        for (int j = 0; j < 4; ++j) ((float4*)dst)[j] = z4;
        return;
    }
    __shared__ short Ksm[2][64][72];
    __shared__ float c2s[16][64];
    int w = t>>6, lane = t&63, l15 = lane&15, quad = lane>>4;
    int sr = t>>2, sc = (t&3)<<4;
    #pragma unroll
    for (int i = 0; i < 4; ++i) {
        int idx = t + i*256;
        int hh = idx >> 6, r = idx & 63;
        c2s[hh][r] = c2ws[((size_t)(b*HH+hh))*SS + q0 + r];
    }
    const short* ksrc = kws + (size_t)(b*SS + k0 + sr)*HD + sc;          // + h*64
    const short* qsrc = qws + (size_t)(b*SS + q0 + w*16 + l15)*HD + quad*8;  // + h*64

    // prologue: stage head 0 K, load head 0 Q frags
    {
        const uint4* kp = (const uint4*)ksrc;
        uint4 c = kp[0], d = kp[1];
        *(uint4*)&Ksm[0][sr][sc] = c;  *(uint4*)&Ksm[0][sr][sc+8] = d;
    }
    bf16x8 qc0 = *(const bf16x8*)(qsrc);
    bf16x8 qc1 = *(const bf16x8*)(qsrc + 32);

    const float SC = 0.125f * 1.4426950408889634f;
    int rowg0 = q0 + w*16 + quad*4;
    f32x4 acc[4] = { {0,0,0,0},{0,0,0,0},{0,0,0,0},{0,0,0,0} };

    for (int h = 0; h < HH; ++h) {
        int cur = h & 1;
        __syncthreads();               // Ksm[cur] (and c2s on h=0) ready
        uint4 nka, nkb; bf16x8 nq0, nq1;
        if (h < HH-1) {
            const uint4* kn = (const uint4*)(ksrc + (h+1)*64);
            nka = kn[0]; nkb = kn[1];
            nq0 = *(const bf16x8*)(qsrc + (h+1)*64);
            nq1 = *(const bf16x8*)(qsrc + (h+1)*64 + 32);
        }

        f32x4 c2 = *(const f32x4*)&c2s[h][w*16 + quad*4];
        #pragma unroll
        for (int ns = 0; ns < 4; ++ns) {
            bf16x8 b0 = *(const bf16x8*)&Ksm[cur][ns*16+l15][quad*8];
            bf16x8 b1 = *(const bf16x8*)&Ksm[cur][ns*16+l15][quad*8+32];
            f32x4 s = {0,0,0,0};
            s = __builtin_amdgcn_mfma_f32_16x16x32_bf16(qc0, b0, s, 0, 0, 0);
            s = __builtin_amdgcn_mfma_f32_16x16x32_bf16(qc1, b1, s, 0, 0, 0);
            int col = k0 + ns*16 + l15;
            #pragma unroll
            for (int r = 0; r < 4; ++r) {
                float ex = __builtin_amdgcn_exp2f(s[r]*SC - c2[r]);
                acc[ns][r] += (col <= rowg0 + r) ? ex : 0.0f;
            }
        }

        if (h < HH-1) {
            int nxt = cur ^ 1;
            *(uint4*)&Ksm[nxt][sr][sc]   = nka;  *(uint4*)&Ksm[nxt][sr][sc+8] = nkb;
            qc0 = nq0; qc1 = nq1;
        }
    }
    #pragma unroll
    for (int ns = 0; ns < 4; ++ns)
        #pragma unroll
        for (int r = 0; r < 4; ++r)
            attn_out[((size_t)(b*SS + rowg0 + r))*SS + k0 + ns*16 + l15] =
                acc[ns][r] * 0.0625f;
}

// ---------------- kernel 4: output projection ----------------
// grid (64, 8): 128x128 tile, BK=64, single-buffer + T2 source-swizzle.
__global__ __launch_bounds__(256) void k_oproj(const short* __restrict__ zws,
        const short* __restrict__ wto, float* __restrict__ outp) {
    __shared__ short As[128*64];
    __shared__ short Bs[128*64];
    int t = threadIdx.x;
    int m0 = blockIdx.x*128, n0 = blockIdx.y*128;
    int lane = t & 63, l15 = lane & 15, quad = lane >> 4;
    int wm = (t>>6) >> 1, wn = (t>>6) & 1;
    f32x4 acc[4][4];
    #pragma unroll
    for (int i=0;i<4;++i)
        #pragma unroll
        for (int c=0;c<4;++c) acc[i][c] = (f32x4){0,0,0,0};

    for (int k0 = 0; k0 < HD; k0 += 64) {
        __syncthreads();
        #pragma unroll
        for (int j = 0; j < 4; ++j) {
            int c = j*256 + t;
            int row = c >> 3, cg = c & 7;
            int cgs = cg ^ (row & 7);
            GLL(zws + (size_t)(m0+row)*HD + k0 + cgs*8, &As[(j*256 + (t & 192))*8]);
            GLL(wto + (size_t)(n0+row)*HD + k0 + cgs*8, &Bs[(j*256 + (t & 192))*8]);
        }
        __syncthreads();
        #pragma unroll
        for (int kp = 0; kp < 64; kp += 32) {
            int pg = ((((kp>>3) + quad) ^ (l15 & 7)) << 3);
            #pragma unroll
            for (int i = 0; i < 4; ++i) {
                bf16x8 a = *(const bf16x8*)&As[(wm*64 + i*16 + l15)*64 + pg];
                #pragma unroll
                for (int c = 0; c < 4; ++c) {
                    bf16x8 b = *(const bf16x8*)&Bs[(wn*64 + c*16 + l15)*64 + pg];
                    acc[i][c] = __builtin_amdgcn_mfma_f32_16x16x32_bf16(a, b, acc[i][c], 0, 0, 0);
                }
            }
        }
    }
    #pragma unroll
    for (int i = 0; i < 4; ++i)
        #pragma unroll
        for (int c = 0; c < 4; ++c)
            #pragma unroll
            for (int r = 0; r < 4; ++r) {
                int row = m0 + wm*64 + i*16 + quad*4 + r;
                int n = n0 + wn*64 + c*16 + l15;
                outp[(size_t)row*EE + n] = acc[i][c][r];
            }
}

extern "C" void kernel_launch(void* const* d_in, const int* in_sizes, int n_in,
                              void* d_out, int out_size, void* d_ws, size_t ws_size,
                              hipStream_t stream) {
    const float* x  = (const float*)d_in[0];
    const float* wq = (const float*)d_in[1];
    const float* wk = (const float*)d_in[2];
    const float* wv = (const float*)d_in[3];
    const float* wo = (const float*)d_in[4];

    short* xbf = (short*)d_ws;                 // 16 MB; reused as z after k_proj
    short* qb  = xbf + QKV_ELEMS;
    short* kb  = qb + QKV_ELEMS;
    short* vtb = kb + QKV_ELEMS;               // V^T [b][h*64+d][pos]
    short* wtq = vtb + QKV_ELEMS;              // 3072x1024 bf16 (n-major)
    short* wto = wtq + (size_t)3*1024*1024;    // 1024x1024 bf16 (n-major)
    float* c2w = (float*)(wto + (size_t)1024*1024);
    short* zb  = xbf;                          // alias: x consumed by k_proj

    float* o = (float*)d_out;
    float* attn_out = o + (size_t)MTOT*EE;

    k_xcast<<<dim3(8192),     256, 0, stream>>>(x, xbf);
    k_wprep<<<dim3(16,64),    256, 0, stream>>>(wq, wk, wv, wo, wtq, wto);
    k_proj <<<dim3(64,24),    256, 0, stream>>>(xbf, wtq, qb);
    k_attnz<<<dim3(8,16,4),   256, 0, stream>>>(qb, kb, vtb, zb, c2w);
    k_mean <<<dim3(32,32,4),  256, 0, stream>>>(qb, kb, c2w, attn_out);
    k_oproj<<<dim3(64,8),     256, 0, stream>>>(zb, wto, o);
}

// Round 9
// 335.835 us; speedup vs baseline: 1.1576x; 1.0403x over previous
//
#include <hip/hip_runtime.h>
#include <stdint.h>

// Attention forward, B=4 S=2048 E=1024 H=16 D=64, causal. Outputs: o fp32 then
// attn.mean(heads) fp32.
//
// R14: k_attnz is VALU-bound (59% VALUBusy vs 19% MfmaUtil). Cuts:
//      (a) softmax scale SC folded into Q at k_proj store time (block-uniform
//          region) -> no v_mul in attnz/mean inner loops;
//      (b) P-pack via v_cvt_pk_bf16_f32 inline asm (2 f32 -> 1 u32 of 2 bf16,
//          T12): 16 cvt_pk replace ~176 slots of manual-RNE f2bf+pack;
//      (c) wave-uniform unmasked fast path (k0+63 <= q0+w*32, ~90% of tiles):
//          no cmp/cndmask.
//      Structure unchanged from R13 (uniform pair-blocks, natural Ps, T2
//      source-swizzle in k_proj/k_oproj).

#define BB 4
#define SS 2048
#define EE 1024
#define HH 16
#define DD 64
#define MTOT (BB*SS)          // 8192
#define HD (HH*DD)            // 1024
#define QKV_ELEMS ((size_t)MTOT*HD)

typedef float f32x4 __attribute__((ext_vector_type(4)));
typedef short bf16x8 __attribute__((ext_vector_type(8)));

#define GLL(g, l) __builtin_amdgcn_global_load_lds( \
    (const __attribute__((address_space(1))) void*)(g), \
    (__attribute__((address_space(3))) void*)(l), 16, 0, 0)

__device__ __forceinline__ short f2bf(float f) {
    unsigned u = __builtin_bit_cast(unsigned, f);
    u += 0x7FFFu + ((u >> 16) & 1u);   // RNE
    return (short)(u >> 16);
}

__device__ __forceinline__ unsigned cvt_pk_bf16(float lo, float hi) {
    unsigned r;
    asm("v_cvt_pk_bf16_f32 %0, %1, %2" : "=v"(r) : "v"(lo), "v"(hi));
    return r;
}

// ---------------- prep 1: x fp32 -> bf16 ----------------
__global__ __launch_bounds__(256) void k_xcast(const float* __restrict__ x,
                                               short* __restrict__ xbf) {
    int i = blockIdx.x*256 + threadIdx.x;
    float4 f = ((const float4*)x)[i];
    short4 s; s.x=f2bf(f.x); s.y=f2bf(f.y); s.z=f2bf(f.z); s.w=f2bf(f.w);
    ((short4*)xbf)[i] = s;
}

// ---------------- prep 2: W -> bf16, transposed to [n][k] ----------------
__global__ __launch_bounds__(256) void k_wprep(const float* __restrict__ wq,
        const float* __restrict__ wk, const float* __restrict__ wv,
        const float* __restrict__ wo, short* __restrict__ wtq,
        short* __restrict__ wto) {
    __shared__ short Tl[64][72];
    int t = threadIdx.x, x = blockIdx.x, y = blockIdx.y;
    int r4 = t >> 2, c4 = (t & 3) << 4;
    if (y < 48) {
        int which = y >> 4, h = y & 15, e0 = x*64;
        const float* src = (which==0?wq:which==1?wk:wv) + (size_t)h*EE*DD;
        const float* p = src + (size_t)(e0 + r4)*DD + c4;
        #pragma unroll
        for (int j = 0; j < 4; ++j) {
            float4 f = ((const float4*)p)[j];
            Tl[r4][c4+j*4+0]=f2bf(f.x); Tl[r4][c4+j*4+1]=f2bf(f.y);
            Tl[r4][c4+j*4+2]=f2bf(f.z); Tl[r4][c4+j*4+3]=f2bf(f.w);
        }
        __syncthreads();
        size_t nrow = ((size_t)(which*16 + h))*64 + r4;   // d = r4
        #pragma unroll
        for (int i = 0; i < 16; ++i)
            wtq[nrow*1024 + e0 + c4 + i] = Tl[c4+i][r4];
    } else {
        int h = y - 48, e0 = x*64;
        const float* src = wo + (size_t)h*DD*EE;          // [d][e]
        const float* p = src + (size_t)r4*EE + e0 + c4;   // d = r4
        #pragma unroll
        for (int j = 0; j < 4; ++j) {
            float4 f = ((const float4*)p)[j];
            Tl[r4][c4+j*4+0]=f2bf(f.x); Tl[r4][c4+j*4+1]=f2bf(f.y);
            Tl[r4][c4+j*4+2]=f2bf(f.z); Tl[r4][c4+j*4+3]=f2bf(f.w);
        }
        __syncthreads();
        #pragma unroll
        for (int i = 0; i < 16; ++i)
            wto[(size_t)(e0 + r4)*1024 + h*64 + c4 + i] = Tl[c4+i][r4];
    }
}

// ---------------- kernel 1: QKV projection ----------------
// grid (64, 24): 128x128 tile, BK=64, single-buffer, T2 source-swizzle.
// Q outputs (blockIdx.y<8) PRE-SCALED by 0.125*log2e. Q,K stored
// [b*S+pos][h*64+d]; V PRE-TRANSPOSED [b][h*64+d][pos].
__global__ __launch_bounds__(256) void k_proj(const short* __restrict__ xbf,
        const short* __restrict__ wtq, short* __restrict__ qkv) {
    __shared__ short As[128*64];
    __shared__ short Bs[128*64];
    int t = threadIdx.x;
    int m0 = blockIdx.x*128, n0 = blockIdx.y*128;
    int lane = t & 63, l15 = lane & 15, quad = lane >> 4;
    int wm = (t>>6) >> 1, wn = (t>>6) & 1;
    f32x4 acc[4][4];
    #pragma unroll
    for (int i=0;i<4;++i)
        #pragma unroll
        for (int c=0;c<4;++c) acc[i][c] = (f32x4){0,0,0,0};

    for (int k0 = 0; k0 < EE; k0 += 64) {
        __syncthreads();
        #pragma unroll
        for (int j = 0; j < 4; ++j) {
            int c = j*256 + t;
            int row = c >> 3, cg = c & 7;
            int cgs = cg ^ (row & 7);            // pre-swizzled source group
            GLL(xbf + (size_t)(m0+row)*EE + k0 + cgs*8, &As[(j*256 + (t & 192))*8]);
            GLL(wtq + (size_t)(n0+row)*EE + k0 + cgs*8, &Bs[(j*256 + (t & 192))*8]);
        }
        __syncthreads();
        #pragma unroll
        for (int kp = 0; kp < 64; kp += 32) {
            int pg = ((((kp>>3) + quad) ^ (l15 & 7)) << 3);   // swizzled read grp
            #pragma unroll
            for (int i = 0; i < 4; ++i) {
                bf16x8 a = *(const bf16x8*)&As[(wm*64 + i*16 + l15)*64 + pg];
                #pragma unroll
                for (int c = 0; c < 4; ++c) {
                    bf16x8 b = *(const bf16x8*)&Bs[(wn*64 + c*16 + l15)*64 + pg];
                    acc[i][c] = __builtin_amdgcn_mfma_f32_16x16x32_bf16(a, b, acc[i][c], 0, 0, 0);
                }
            }
        }
    }
    // Q region (blockIdx.y<8): fold softmax scale into Q once here.
    float qscale = (blockIdx.y < 8) ? (0.125f * 1.4426950408889634f) : 1.0f;
    short* vt = qkv + 2*QKV_ELEMS;
    #pragma unroll
    for (int i = 0; i < 4; ++i)
        #pragma unroll
        for (int c = 0; c < 4; ++c) {
            int n = n0 + wn*64 + c*16 + l15;
            int row = m0 + wm*64 + i*16 + quad*4;
            if (n < 2048) {          // Q or K: [region][b*S+pos][h*64+d]
                #pragma unroll
                for (int r = 0; r < 4; ++r)
                    qkv[(size_t)(n>>10)*QKV_ELEMS + (size_t)(row+r)*HD + (n & 1023)] =
                        f2bf(acc[i][c][r] * qscale);
            } else {                 // V: [b][h*64+d][pos], pos contiguous in r
                short4 s4;
                s4.x = f2bf(acc[i][c][0]); s4.y = f2bf(acc[i][c][1]);
                s4.z = f2bf(acc[i][c][2]); s4.w = f2bf(acc[i][c][3]);
                int bb_ = row >> 11, pos = row & 2047;
                *(short4*)&vt[((size_t)bb_*HD + (n - 2048))*SS + pos] = s4;
            }
        }
}

// ---------- kernel 2: z = softmax(QK^T) V (Q pre-scaled); c2=log2(l) ----------
// grid (8, 16, 4): q-tiles {qx, 15-qx} sequentially (uniform 34 tiles/block).
// Swapped QK^T -> packed P-writes via v_cvt_pk_bf16_f32; natural Ps layout;
// wave-uniform unmasked fast path; T14 prefetch, setprio.
__global__ __launch_bounds__(256) void k_attnz(const short* __restrict__ qws,
        const short* __restrict__ kws, const short* __restrict__ vtg,
        short* __restrict__ zws, float* __restrict__ c2ws) {
    __shared__ short Ks[64][72];
    __shared__ short Vt[64][72];
    __shared__ short Ps[4][32][72];   // per-wave P tile (no barrier needed)
    int t = threadIdx.x;
    int h = blockIdx.y, b = blockIdx.z;
    int w = t>>6, lane = t&63, l15 = lane&15, quad = lane>>4;
    int sr = t>>2, sc = (t&3)<<4;

    const short* ksrc = kws + (size_t)(b*SS + sr)*HD + h*DD + sc;
    const short* vsrc = vtg + ((size_t)b*HD + h*DD + sr)*SS + sc;

    bf16x8 ones;
    #pragma unroll
    for (int i=0;i<8;++i) ones[i] = (short)0x3F80;   // bf16 1.0

    for (int half = 0; half < 2; ++half) {
        int qx = half ? (15 - (int)blockIdx.x) : (int)blockIdx.x;
        int q0 = qx*128;

        bf16x8 qr[2][2];                  // Q fragments, loop-invariant per half
        #pragma unroll
        for (int mf=0; mf<2; ++mf)
            #pragma unroll
            for (int kp=0; kp<2; ++kp)
                qr[mf][kp] = *(const bf16x8*)(qws +
                    (size_t)(b*SS + q0 + w*32 + mf*16 + l15)*HD + h*DD + kp*32 + quad*8);

        f32x4 accz[2][4];
        f32x4 accl[2];
        #pragma unroll
        for (int mf=0;mf<2;++mf) {
            accl[mf] = (f32x4){0,0,0,0};
            #pragma unroll
            for (int c=0;c<4;++c) accz[mf][c] = (f32x4){0,0,0,0};
        }
        int nk = q0/64 + 2;
        int qmax = q0 + w*32 + 31;

        uint4 pk0 = ((const uint4*)ksrc)[0], pk1 = ((const uint4*)ksrc)[1];
        uint4 pv0 = ((const uint4*)vsrc)[0], pv1 = ((const uint4*)vsrc)[1];

        for (int kt = 0; kt < nk; ++kt) {
            int k0 = kt*64;
            __syncthreads();               // prior compute done reading LDS
            *(uint4*)&Ks[sr][sc]   = pk0;  *(uint4*)&Ks[sr][sc+8] = pk1;
            *(uint4*)&Vt[sr][sc]   = pv0;  *(uint4*)&Vt[sr][sc+8] = pv1;
            __syncthreads();               // tile ready
            if (kt+1 < nk) {               // T14: issue next tile under compute
                const uint4* kn = (const uint4*)(ksrc + (size_t)(k0+64)*HD);
                const uint4* vn = (const uint4*)(vsrc + (k0+64));
                pk0=kn[0]; pk1=kn[1]; pv0=vn[0]; pv1=vn[1];
            }
            if (k0 > qmax) continue;       // fully masked for this wave

            // QK^T swapped: s[mf][c] -> col(l15)=q-row(mf*16+l15),
            // row(quad*4+r)=k-pos(c*16+quad*4+r). Q pre-scaled -> s is log2-domain.
            f32x4 s[2][4];
            #pragma unroll
            for (int mf=0;mf<2;++mf)
                #pragma unroll
                for (int c=0;c<4;++c) s[mf][c] = (f32x4){0,0,0,0};
            __builtin_amdgcn_s_setprio(1);
            #pragma unroll
            for (int c=0;c<4;++c)
                #pragma unroll
                for (int kp=0;kp<2;++kp) {
                    bf16x8 aK = *(const bf16x8*)&Ks[c*16+l15][kp*32+quad*8];
                    s[0][c] = __builtin_amdgcn_mfma_f32_16x16x32_bf16(aK, qr[0][kp], s[0][c], 0, 0, 0);
                    s[1][c] = __builtin_amdgcn_mfma_f32_16x16x32_bf16(aK, qr[1][kp], s[1][c], 0, 0, 0);
                }
            __builtin_amdgcn_s_setprio(0);
            // P epilogue: packed cvt_pk writes, natural layout.
            if (k0 + 63 <= q0 + w*32) {    // wave-uniform: fully unmasked tile
                #pragma unroll
                for (int mf=0;mf<2;++mf)
                    #pragma unroll
                    for (int c=0;c<4;++c) {
                        float e0 = __builtin_amdgcn_exp2f(s[mf][c][0]);
                        float e1 = __builtin_amdgcn_exp2f(s[mf][c][1]);
                        float e2 = __builtin_amdgcn_exp2f(s[mf][c][2]);
                        float e3 = __builtin_amdgcn_exp2f(s[mf][c][3]);
                        uint2 u; u.x = cvt_pk_bf16(e0, e1); u.y = cvt_pk_bf16(e2, e3);
                        *(uint2*)&Ps[w][mf*16 + l15][c*16 + quad*4] = u;
                    }
            } else {                       // diagonal band: per-element mask
                #pragma unroll
                for (int mf=0;mf<2;++mf) {
                    int qg = q0 + w*32 + mf*16 + l15;
                    #pragma unroll
                    for (int c=0;c<4;++c) {
                        int kb = k0 + c*16 + quad*4;
                        float e[4];
                        #pragma unroll
                        for (int r=0;r<4;++r)
                            e[r] = (kb + r <= qg) ? __builtin_amdgcn_exp2f(s[mf][c][r]) : 0.0f;
                        uint2 u; u.x = cvt_pk_bf16(e[0], e[1]); u.y = cvt_pk_bf16(e[2], e[3]);
                        *(uint2*)&Ps[w][mf*16 + l15][c*16 + quad*4] = u;
                    }
                }
            }
            // Ps is wave-private: HW lgkmcnt ordering suffices, no barrier.
            __builtin_amdgcn_s_setprio(1);
            #pragma unroll
            for (int kp=0;kp<2;++kp) {
                bf16x8 pa0 = *(const bf16x8*)&Ps[w][l15][kp*32+quad*8];
                bf16x8 pa1 = *(const bf16x8*)&Ps[w][16+l15][kp*32+quad*8];
                #pragma unroll
                for (int cc=0;cc<4;++cc) {
                    bf16x8 vb = *(const bf16x8*)&Vt[cc*16+l15][kp*32+quad*8];
                    accz[0][cc] = __builtin_amdgcn_mfma_f32_16x16x32_bf16(pa0, vb, accz[0][cc], 0, 0, 0);
                    accz[1][cc] = __builtin_amdgcn_mfma_f32_16x16x32_bf16(pa1, vb, accz[1][cc], 0, 0, 0);
                }
                accl[0] = __builtin_amdgcn_mfma_f32_16x16x32_bf16(pa0, ones, accl[0], 0, 0, 0);
                accl[1] = __builtin_amdgcn_mfma_f32_16x16x32_bf16(pa1, ones, accl[1], 0, 0, 0);
            }
            __builtin_amdgcn_s_setprio(0);
        }
        #pragma unroll
        for (int mf=0;mf<2;++mf) {
            float il[4];
            #pragma unroll
            for (int r=0;r<4;++r) il[r] = 1.0f / accl[mf][r];
            #pragma unroll
            for (int cc=0;cc<4;++cc)
                #pragma unroll
                for (int r=0;r<4;++r) {
                    int row = q0 + w*32 + mf*16 + quad*4 + r;
                    zws[(size_t)(b*SS+row)*HD + h*DD + cc*16 + l15] = f2bf(accz[mf][cc][r]*il[r]);
                }
            if (l15 == 0) {
                size_t base = ((size_t)(b*HH+h))*SS + q0 + w*32 + mf*16 + quad*4;
                #pragma unroll
                for (int r=0;r<4;++r)
                    c2ws[base+r] = __log2f(accl[mf][r]);
            }
        }
    }
}

// ---------------- kernel 3: attn mean over heads ----------------
// grid (32, 32, 4). Upper-triangle blocks write zeros. Only K staged in LDS;
// Q (pre-scaled) frags prefetched to regs. ex = exp2(s - c2).
__global__ __launch_bounds__(256) void k_mean(const short* __restrict__ qws,
        const short* __restrict__ kws, const float* __restrict__ c2ws,
        float* __restrict__ attn_out) {
    int b = blockIdx.z;
    int qx = (b & 1) ? (31 - (int)blockIdx.x) : (int)blockIdx.x;
    int q0 = qx*64, k0 = blockIdx.y*64;
    int t = threadIdx.x;
    if (k0 > q0) {
        int r = t >> 2, cq = (t & 3) << 4;
        float4 z4 = {0.f,0.f,0.f,0.f};
        float* dst = attn_out + ((size_t)(b*SS + q0 + r))*SS + k0 + cq;
        #pragma unroll
        for (int j = 0; j < 4; ++j) ((float4*)dst)[j] = z4;
        return;
    }
    __shared__ short Ksm[2][64][72];
    __shared__ float c2s[16][64];
    int w = t>>6, lane = t&63, l15 = lane&15, quad = lane>>4;
    int sr = t>>2, sc = (t&3)<<4;
    #pragma unroll
    for (int i = 0; i < 4; ++i) {
        int idx = t + i*256;
        int hh = idx >> 6, r = idx & 63;
        c2s[hh][r] = c2ws[((size_t)(b*HH+hh))*SS + q0 + r];
    }
    const short* ksrc = kws + (size_t)(b*SS + k0 + sr)*HD + sc;          // + h*64
    const short* qsrc = qws + (size_t)(b*SS + q0 + w*16 + l15)*HD + quad*8;  // + h*64

    // prologue: stage head 0 K, load head 0 Q frags
    {
        const uint4* kp = (const uint4*)ksrc;
        uint4 c = kp[0], d = kp[1];
        *(uint4*)&Ksm[0][sr][sc] = c;  *(uint4*)&Ksm[0][sr][sc+8] = d;
    }
    bf16x8 qc0 = *(const bf16x8*)(qsrc);
    bf16x8 qc1 = *(const bf16x8*)(qsrc + 32);

    int rowg0 = q0 + w*16 + quad*4;
    f32x4 acc[4] = { {0,0,0,0},{0,0,0,0},{0,0,0,0},{0,0,0,0} };

    for (int h = 0; h < HH; ++h) {
        int cur = h & 1;
        __syncthreads();               // Ksm[cur] (and c2s on h=0) ready
        uint4 nka, nkb; bf16x8 nq0, nq1;
        if (h < HH-1) {
            const uint4* kn = (const uint4*)(ksrc + (h+1)*64);
            nka = kn[0]; nkb = kn[1];
            nq0 = *(const bf16x8*)(qsrc + (h+1)*64);
            nq1 = *(const bf16x8*)(qsrc + (h+1)*64 + 32);
        }

        f32x4 c2 = *(const f32x4*)&c2s[h][w*16 + quad*4];
        #pragma unroll
        for (int ns = 0; ns < 4; ++ns) {
            bf16x8 b0 = *(const bf16x8*)&Ksm[cur][ns*16+l15][quad*8];
            bf16x8 b1 = *(const bf16x8*)&Ksm[cur][ns*16+l15][quad*8+32];
            f32x4 s = {0,0,0,0};
            s = __builtin_amdgcn_mfma_f32_16x16x32_bf16(qc0, b0, s, 0, 0, 0);
            s = __builtin_amdgcn_mfma_f32_16x16x32_bf16(qc1, b1, s, 0, 0, 0);
            int col = k0 + ns*16 + l15;
            #pragma unroll
            for (int r = 0; r < 4; ++r) {
                float ex = __builtin_amdgcn_exp2f(s[r] - c2[r]);
                acc[ns][r] += (col <= rowg0 + r) ? ex : 0.0f;
            }
        }

        if (h < HH-1) {
            int nxt = cur ^ 1;
            *(uint4*)&Ksm[nxt][sr][sc]   = nka;  *(uint4*)&Ksm[nxt][sr][sc+8] = nkb;
            qc0 = nq0; qc1 = nq1;
        }
    }
    #pragma unroll
    for (int ns = 0; ns < 4; ++ns)
        #pragma unroll
        for (int r = 0; r < 4; ++r)
            attn_out[((size_t)(b*SS + rowg0 + r))*SS + k0 + ns*16 + l15] =
                acc[ns][r] * 0.0625f;
}

// ---------------- kernel 4: output projection ----------------
// grid (64, 8): 128x128 tile, BK=64, single-buffer + T2 source-swizzle.
__global__ __launch_bounds__(256) void k_oproj(const short* __restrict__ zws,
        const short* __restrict__ wto, float* __restrict__ outp) {
    __shared__ short As[128*64];
    __shared__ short Bs[128*64];
    int t = threadIdx.x;
    int m0 = blockIdx.x*128, n0 = blockIdx.y*128;
    int lane = t & 63, l15 = lane & 15, quad = lane >> 4;
    int wm = (t>>6) >> 1, wn = (t>>6) & 1;
    f32x4 acc[4][4];
    #pragma unroll
    for (int i=0;i<4;++i)
        #pragma unroll
        for (int c=0;c<4;++c) acc[i][c] = (f32x4){0,0,0,0};

    for (int k0 = 0; k0 < HD; k0 += 64) {
        __syncthreads();
        #pragma unroll
        for (int j = 0; j < 4; ++j) {
            int c = j*256 + t;
            int row = c >> 3, cg = c & 7;
            int cgs = cg ^ (row & 7);
            GLL(zws + (size_t)(m0+row)*HD + k0 + cgs*8, &As[(j*256 + (t & 192))*8]);
            GLL(wto + (size_t)(n0+row)*HD + k0 + cgs*8, &Bs[(j*256 + (t & 192))*8]);
        }
        __syncthreads();
        #pragma unroll
        for (int kp = 0; kp < 64; kp += 32) {
            int pg = ((((kp>>3) + quad) ^ (l15 & 7)) << 3);
            #pragma unroll
            for (int i = 0; i < 4; ++i) {
                bf16x8 a = *(const bf16x8*)&As[(wm*64 + i*16 + l15)*64 + pg];
                #pragma unroll
                for (int c = 0; c < 4; ++c) {
                    bf16x8 b = *(const bf16x8*)&Bs[(wn*64 + c*16 + l15)*64 + pg];
                    acc[i][c] = __builtin_amdgcn_mfma_f32_16x16x32_bf16(a, b, acc[i][c], 0, 0, 0);
                }
            }
        }
    }
    #pragma unroll
    for (int i = 0; i < 4; ++i)
        #pragma unroll
        for (int c = 0; c < 4; ++c)
            #pragma unroll
            for (int r = 0; r < 4; ++r) {
                int row = m0 + wm*64 + i*16 + quad*4 + r;
                int n = n0 + wn*64 + c*16 + l15;
                outp[(size_t)row*EE + n] = acc[i][c][r];
            }
}

extern "C" void kernel_launch(void* const* d_in, const int* in_sizes, int n_in,
                              void* d_out, int out_size, void* d_ws, size_t ws_size,
                              hipStream_t stream) {
    const float* x  = (const float*)d_in[0];
    const float* wq = (const float*)d_in[1];
    const float* wk = (const float*)d_in[2];
    const float* wv = (const float*)d_in[3];
    const float* wo = (const float*)d_in[4];

    short* xbf = (short*)d_ws;                 // 16 MB; reused as z after k_proj
    short* qb  = xbf + QKV_ELEMS;
    short* kb  = qb + QKV_ELEMS;
    short* vtb = kb + QKV_ELEMS;               // V^T [b][h*64+d][pos]
    short* wtq = vtb + QKV_ELEMS;              // 3072x1024 bf16 (n-major)
    short* wto = wtq + (size_t)3*1024*1024;    // 1024x1024 bf16 (n-major)
    float* c2w = (float*)(wto + (size_t)1024*1024);
    short* zb  = xbf;                          // alias: x consumed by k_proj

    float* o = (float*)d_out;
    float* attn_out = o + (size_t)MTOT*EE;

    k_xcast<<<dim3(8192),     256, 0, stream>>>(x, xbf);
    k_wprep<<<dim3(16,64),    256, 0, stream>>>(wq, wk, wv, wo, wtq, wto);
    k_proj <<<dim3(64,24),    256, 0, stream>>>(xbf, wtq, qb);
    k_attnz<<<dim3(8,16,4),   256, 0, stream>>>(qb, kb, vtb, zb, c2w);
    k_mean <<<dim3(32,32,4),  256, 0, stream>>>(qb, kb, c2w, attn_out);
    k_oproj<<<dim3(64,8),     256, 0, stream>>>(zb, wto, o);
}